// Round 1
// baseline (219.708 us; speedup 1.0000x reference)
//
#include <hip/hip_runtime.h>
#include <hip/hip_bf16.h>

#define B_ 16
#define N_ 512
#define F_ 32
#define T_ 24
#define K_ 3
#define C_ 64
#define FT_ 768   // F_*T_
#define KF_ 96    // K_*F_

typedef __attribute__((ext_vector_type(8))) short bf16x8;
typedef __attribute__((ext_vector_type(4))) float f32x4;

// f32 -> bf16 with round-to-nearest-even
static __device__ __forceinline__ ushort f2b(float x) {
  uint u = __float_as_uint(x);
  return (ushort)((u + 0x7fffu + ((u >> 16) & 1u)) >> 16);
}
static __device__ __forceinline__ uint pk2(float a, float b) {
  return (uint)f2b(a) | ((uint)f2b(b) << 16);
}

// Stage 1: R[k][b][ft][m] (bf16) = sum_n X[b][n][ft] * cheb[k][n][m] * s_a[b][n][m]
// Tile: 128 (ft) x 128 (m), contraction n in steps of 64. 256 threads = 4 waves (2x2).
__global__ __launch_bounds__(256, 2)
void stage1_kernel(const float* __restrict__ X, const float* __restrict__ SA,
                   const float* __restrict__ CH, ushort* __restrict__ R)
{
  __shared__ __align__(16) ushort Xs[128 * 64];  // [ft_local][n_local], XOR-swizzled
  __shared__ __align__(16) ushort As[128 * 64];  // [m_local][n_local], XOR-swizzled

  const int kb = blockIdx.y;
  const int k = kb / B_;
  const int b = kb - k * B_;
  const int ft0 = (blockIdx.x >> 2) * 128;  // 6 ft-tiles
  const int m0  = (blockIdx.x & 3) * 128;   // 4 m-tiles

  const int tid  = threadIdx.x;
  const int lane = tid & 63;
  const int wid  = tid >> 6;
  const int wft  = (wid >> 1) * 64;  // wave's ft sub-tile
  const int wm   = (wid & 1) * 64;   // wave's m sub-tile

  // staging assignment: row = ft_local (for Xs) / m_local (for As), covers 32 n each
  const int srow  = tid & 127;
  const int shalf = (tid >> 7) * 32;
  const int swz   = (srow & 7) << 4;

  const float* Xp = X  + (size_t)b * N_ * FT_ + (ft0 + srow);
  const float* Sp = SA + (size_t)b * N_ * N_  + (m0 + srow);
  const float* Cp = CH + (size_t)k * N_ * N_  + (m0 + srow);

  f32x4 acc[4][4];
#pragma unroll
  for (int i = 0; i < 4; ++i)
#pragma unroll
    for (int j = 0; j < 4; ++j)
      acc[i][j] = (f32x4){0.f, 0.f, 0.f, 0.f};

  char* XsRow = (char*)Xs + srow * 128;
  char* AsRow = (char*)As + srow * 128;

  for (int nb = 0; nb < 8; ++nb) {
    const int n0 = nb * 64;
    __syncthreads();
    // --- transposed staging: global [n][row-contig] -> LDS [row][n-contig] (bf16)
#pragma unroll
    for (int c = 0; c < 4; ++c) {
      const int nl0 = shalf + c * 8;
      const float* xp = Xp + (size_t)(n0 + nl0) * FT_;
      uint4 px;
      px.x = pk2(xp[0 * FT_], xp[1 * FT_]);
      px.y = pk2(xp[2 * FT_], xp[3 * FT_]);
      px.z = pk2(xp[4 * FT_], xp[5 * FT_]);
      px.w = pk2(xp[6 * FT_], xp[7 * FT_]);
      *(uint4*)(XsRow + ((nl0 * 2) ^ swz)) = px;

      const float* sp = Sp + (size_t)(n0 + nl0) * N_;
      const float* cp = Cp + (size_t)(n0 + nl0) * N_;
      uint4 pa;
      pa.x = pk2(cp[0 * N_] * sp[0 * N_], cp[1 * N_] * sp[1 * N_]);
      pa.y = pk2(cp[2 * N_] * sp[2 * N_], cp[3 * N_] * sp[3 * N_]);
      pa.z = pk2(cp[4 * N_] * sp[4 * N_], cp[5 * N_] * sp[5 * N_]);
      pa.w = pk2(cp[6 * N_] * sp[6 * N_], cp[7 * N_] * sp[7 * N_]);
      *(uint4*)(AsRow + ((nl0 * 2) ^ swz)) = pa;
    }
    __syncthreads();

    // --- MFMA: D[ft,m] += X^T-frag x A-frag, two K=32 chunks
#pragma unroll
    for (int kk = 0; kk < 2; ++kk) {
      const int colb = kk * 64 + ((lane >> 4) << 4);  // byte offset of 8 bf16 along n
      bf16x8 af[4], bfr[4];
#pragma unroll
      for (int i = 0; i < 4; ++i) {
        const int r = wft + i * 16 + (lane & 15);
        af[i] = *(const bf16x8*)((const char*)Xs + r * 128 + (colb ^ ((r & 7) << 4)));
      }
#pragma unroll
      for (int j = 0; j < 4; ++j) {
        const int r = wm + j * 16 + (lane & 15);
        bfr[j] = *(const bf16x8*)((const char*)As + r * 128 + (colb ^ ((r & 7) << 4)));
      }
#pragma unroll
      for (int i = 0; i < 4; ++i)
#pragma unroll
        for (int j = 0; j < 4; ++j)
          acc[i][j] = __builtin_amdgcn_mfma_f32_16x16x32_bf16(af[i], bfr[j], acc[i][j], 0, 0, 0);
    }
  }

  // --- epilogue: D layout col=lane&15 (m), row=(lane>>4)*4+reg (ft); store bf16
  ushort* Rb = R + (size_t)(k * B_ + b) * FT_ * N_;
  const int col = lane & 15;
  const int rg4 = (lane >> 4) * 4;
#pragma unroll
  for (int i = 0; i < 4; ++i) {
#pragma unroll
    for (int r = 0; r < 4; ++r) {
      const int ft = ft0 + wft + i * 16 + rg4 + r;
      ushort* rp = Rb + (size_t)ft * N_ + (m0 + wm + col);
#pragma unroll
      for (int j = 0; j < 4; ++j)
        rp[j * 16] = f2b(acc[i][j][r]);
    }
  }
}

// Stage 2: out[t][b][m][o] = relu( sum_{kf} R[k][b][f*T_+t][m] * Theta[k][f][o] )
// Block: (b, t, m-tile of 128). Thread: 4 m x 8 o outer product, kf in chunks of 8.
__global__ __launch_bounds__(256, 2)
void stage2_kernel(const ushort* __restrict__ R, const float* __restrict__ TH,
                   float* __restrict__ Out)
{
  __shared__ float Th[KF_ * C_];  // 96x64 f32, layout == flat Theta
  __shared__ float Rs[8 * 128];   // [kf_chunk][m_local]

  const int m0 = blockIdx.x * 128;
  const int t  = blockIdx.y;
  const int b  = blockIdx.z;
  const int tid = threadIdx.x;

  for (int i = tid; i < KF_ * C_; i += 256) Th[i] = TH[i];

  const int tm = tid >> 3;         // 0..31 -> m = m0 + tm*4
  const int to = (tid & 7) * 8;    // o base

  float acc[4][8];
#pragma unroll
  for (int i = 0; i < 4; ++i)
#pragma unroll
    for (int j = 0; j < 8; ++j) acc[i][j] = 0.f;

  const int kfi = tid >> 5;        // 0..7 (staging)
  const int ml  = (tid & 31) * 4;

  for (int kfc = 0; kfc < 12; ++kfc) {
    const int kf = kfc * 8 + kfi;
    const int kq = kf >> 5;        // k
    const int f  = kf & 31;
    const ushort* rp = R + (((size_t)(kq * B_ + b) * FT_ + f * T_ + t) * N_) + m0 + ml;
    const ushort4 rv = *(const ushort4*)rp;  // coalesced along m
    __syncthreads();               // previous chunk's compute done (also fences Th on iter 0)
    float4 w;
    w.x = __uint_as_float((uint)rv.x << 16);
    w.y = __uint_as_float((uint)rv.y << 16);
    w.z = __uint_as_float((uint)rv.z << 16);
    w.w = __uint_as_float((uint)rv.w << 16);
    *(float4*)&Rs[kfi * 128 + ml] = w;
    __syncthreads();
#pragma unroll
    for (int q = 0; q < 8; ++q) {
      const int kf2 = kfc * 8 + q;
      const float4 av = *(const float4*)&Rs[q * 128 + tm * 4];
      const float* thp = &Th[kf2 * 64 + to];
#pragma unroll
      for (int j = 0; j < 8; ++j) {
        const float th = thp[j];
        acc[0][j] += av.x * th;
        acc[1][j] += av.y * th;
        acc[2][j] += av.z * th;
        acc[3][j] += av.w * th;
      }
    }
  }

  float* ob = Out + (((size_t)t * B_ + b) * N_ + (m0 + tm * 4)) * C_ + to;
#pragma unroll
  for (int i = 0; i < 4; ++i) {
    float4 v0, v1;
    v0.x = fmaxf(acc[i][0], 0.f); v0.y = fmaxf(acc[i][1], 0.f);
    v0.z = fmaxf(acc[i][2], 0.f); v0.w = fmaxf(acc[i][3], 0.f);
    v1.x = fmaxf(acc[i][4], 0.f); v1.y = fmaxf(acc[i][5], 0.f);
    v1.z = fmaxf(acc[i][6], 0.f); v1.w = fmaxf(acc[i][7], 0.f);
    *(float4*)(ob + (size_t)i * C_)     = v0;
    *(float4*)(ob + (size_t)i * C_ + 4) = v1;
  }
}

extern "C" void kernel_launch(void* const* d_in, const int* in_sizes, int n_in,
                              void* d_out, int out_size, void* d_ws, size_t ws_size,
                              hipStream_t stream) {
  const float* X  = (const float*)d_in[0];  // [16,512,32,24]
  const float* SA = (const float*)d_in[1];  // [16,512,512]
  const float* CH = (const float*)d_in[2];  // [3,512,512]
  const float* TH = (const float*)d_in[3];  // [3,32,64]
  float* Out = (float*)d_out;               // [24,16,512,64]
  ushort* R = (ushort*)d_ws;                // bf16 [3,16,768,512] = 37.7 MB

  dim3 g1(24, K_ * B_);          // 24 tiles x 48 (k,b)
  stage1_kernel<<<g1, 256, 0, stream>>>(X, SA, CH, R);
  dim3 g2(4, T_, B_);            // 4 m-tiles x 24 t x 16 b
  stage2_kernel<<<g2, 256, 0, stream>>>(R, TH, Out);
}

// Round 3
// 161.316 us; speedup vs baseline: 1.3620x; 1.3620x over previous
//
#include <hip/hip_runtime.h>
#include <hip/hip_bf16.h>

#define B_ 16
#define N_ 512
#define F_ 32
#define T_ 24
#define K_ 3
#define C_ 64
#define FT_ 768   // F_*T_
#define KF_ 96    // K_*F_

typedef __attribute__((ext_vector_type(8))) short bf16x8;
typedef __attribute__((ext_vector_type(4))) float f32x4;

static __device__ __forceinline__ ushort f2b(float x) {
  uint u = __float_as_uint(x);
  return (ushort)((u + 0x7fffu + ((u >> 16) & 1u)) >> 16);
}
static __device__ __forceinline__ uint pk2(float a, float b) {
  return (uint)f2b(a) | ((uint)f2b(b) << 16);
}

#define GLOAD_LDS16(g, l)                                                     \
  __builtin_amdgcn_global_load_lds(                                           \
      (const __attribute__((address_space(1))) void*)(g),                     \
      (__attribute__((address_space(3))) void*)(l), 16, 0, 0)

// ---------------- prep kernels ----------------

// Xt2[b][t*32+f][n] (bf16) = X[b][n][f*24+t]
__global__ __launch_bounds__(256) void prepX(const float* __restrict__ X,
                                             ushort* __restrict__ Xt2) {
  __shared__ ushort L[32 * FT_];  // 48 KB, [n_local][ft] linear
  const int b = blockIdx.y;
  const int n0 = blockIdx.x * 32;
  const int tid = threadIdx.x;

  const float* Xp = X + ((size_t)b * N_ + n0) * FT_;
#pragma unroll
  for (int it = 0; it < 24; ++it) {
    int idx = tid + it * 256;        // over 32*192 float4
    int row = idx / 192, c4 = idx % 192;
    float4 v = *(const float4*)(Xp + (size_t)row * FT_ + c4 * 4);
    uint2 p; p.x = pk2(v.x, v.y); p.y = pk2(v.z, v.w);
    *(uint2*)&L[row * FT_ + c4 * 4] = p;
  }
  __syncthreads();
#pragma unroll
  for (int j = 0; j < 3; ++j) {
    int ft2 = j * 256 + tid;         // t*32+f
    int t = ft2 >> 5, f = ft2 & 31;
    int incol = f * T_ + t;
    ushort tmp[32];
#pragma unroll
    for (int r = 0; r < 32; ++r) tmp[r] = L[r * FT_ + incol];
    uint wv[16];
#pragma unroll
    for (int q = 0; q < 16; ++q)
      wv[q] = (uint)tmp[2 * q] | ((uint)tmp[2 * q + 1] << 16);
    ushort* op = Xt2 + ((size_t)b * FT_ + ft2) * N_ + n0;
#pragma unroll
    for (int q = 0; q < 4; ++q) {
      uint4 w; w.x = wv[4*q]; w.y = wv[4*q+1]; w.z = wv[4*q+2]; w.w = wv[4*q+3];
      *((uint4*)op + q) = w;
    }
  }
}

// At[k*16+b][m][n] (bf16) = CH[k][n][m] * SA[b][n][m]   (n<->m transpose)
__global__ __launch_bounds__(256) void prepA(const float* __restrict__ SA,
                                             const float* __restrict__ CH,
                                             ushort* __restrict__ At) {
  const int kb = blockIdx.y;
  const int k = kb >> 4, b = kb & 15;
  const int m0 = (blockIdx.x & 7) * 64, n0 = (blockIdx.x >> 3) * 64;
  const int tid = threadIdx.x;
  const int ml = (tid & 15) * 4, nl = (tid >> 4) * 4;

  const float* cp = CH + ((size_t)k * N_ + n0 + nl) * N_ + m0 + ml;
  const float* sp = SA + ((size_t)b * N_ + n0 + nl) * N_ + m0 + ml;
  float4 p[4];
#pragma unroll
  for (int q = 0; q < 4; ++q) {
    float4 c = *(const float4*)(cp + (size_t)q * N_);
    float4 s = *(const float4*)(sp + (size_t)q * N_);
    p[q] = make_float4(c.x * s.x, c.y * s.y, c.z * s.z, c.w * s.w);
  }
  ushort* ob = At + (size_t)kb * N_ * N_ + (size_t)(m0 + ml) * N_ + n0 + nl;
#pragma unroll
  for (int s = 0; s < 4; ++s) {
    uint2 w;
    w.x = pk2(((const float*)&p[0])[s], ((const float*)&p[1])[s]);
    w.y = pk2(((const float*)&p[2])[s], ((const float*)&p[3])[s]);
    *(uint2*)(ob + (size_t)s * N_) = w;
  }
}

// Th2[o][k*32+f] (bf16) = Theta[k][f][o]
__global__ __launch_bounds__(256) void prepTh(const float* __restrict__ TH,
                                              ushort* __restrict__ Th2) {
  const int tid = threadIdx.x;
  const int o = tid & 63, g = tid >> 6;
#pragma unroll
  for (int q = 0; q < 24; ++q) {
    int kf = g * 24 + q;
    Th2[o * KF_ + kf] = f2b(TH[(size_t)kf * C_ + o]);
  }
}

// ---------------- stage 1: GEMM (m97 structure) ----------------
// R2[b][t][m][k*32+f] = sum_n Xt2[b][t*32+f][n] * At[k*16+b][m][n]
__global__ __launch_bounds__(256, 2) void stage1(const ushort* __restrict__ Xt2,
                                                 const ushort* __restrict__ At,
                                                 ushort* __restrict__ R2) {
  __shared__ __align__(16) ushort Abuf[128 * 64];
  __shared__ __align__(16) ushort Bbuf[128 * 64];
  const int kb = blockIdx.y;
  const int k = kb >> 4, b = kb & 15;
  const int ft0 = (blockIdx.x >> 2) * 128;
  const int m0 = (blockIdx.x & 3) * 128;
  const int tid = threadIdx.x, lane = tid & 63, wid = tid >> 6;
  const int wft = (wid >> 1) * 64, wm = (wid & 1) * 64;

  const char* Xbase = (const char*)(Xt2 + ((size_t)b * FT_ + ft0) * N_);
  const char* Bbase = (const char*)(At + ((size_t)kb * N_ + m0) * N_);
  const int srow = lane >> 3;
  const int scol = (lane & 7) * 16;

  f32x4 acc[4][4];
#pragma unroll
  for (int i = 0; i < 4; ++i)
#pragma unroll
    for (int j = 0; j < 4; ++j) acc[i][j] = (f32x4){0.f, 0.f, 0.f, 0.f};

  for (int nb = 0; nb < 8; ++nb) {
    __syncthreads();
#pragma unroll
    for (int c = 0; c < 4; ++c) {
      const int s = wid * 4 + c;                    // 16 segs x 1KB per tile
      const size_t go = (size_t)(s * 8 + srow) * 1024 + nb * 128 + scol;
      GLOAD_LDS16(Xbase + go, (char*)Abuf + s * 1024);
      GLOAD_LDS16(Bbase + go, (char*)Bbuf + s * 1024);
    }
    __syncthreads();
#pragma unroll
    for (int kk = 0; kk < 2; ++kk) {
      const int cb = kk * 64 + (lane >> 4) * 16;
      bf16x8 af[4], bfv[4];
#pragma unroll
      for (int i = 0; i < 4; ++i)
        af[i] = *(const bf16x8*)((const char*)Abuf + (wft + i * 16 + (lane & 15)) * 128 + cb);
#pragma unroll
      for (int j = 0; j < 4; ++j)
        bfv[j] = *(const bf16x8*)((const char*)Bbuf + (wm + j * 16 + (lane & 15)) * 128 + cb);
#pragma unroll
      for (int i = 0; i < 4; ++i)
#pragma unroll
        for (int j = 0; j < 4; ++j)
          acc[i][j] = __builtin_amdgcn_mfma_f32_16x16x32_bf16(af[i], bfv[j], acc[i][j], 0, 0, 0);
    }
  }

  // epilogue: D row=(lane>>4)*4+reg (ft''), col=lane&15 (m); pack 4 f -> 8B
  const int col = lane & 15, rg4 = (lane >> 4) * 4;
#pragma unroll
  for (int i = 0; i < 4; ++i) {
    const int rowl = wft + i * 16 + rg4;
    const int ft2 = ft0 + rowl;
    const int t = ft2 >> 5, f = ft2 & 31;
#pragma unroll
    for (int j = 0; j < 4; ++j) {
      const int m = m0 + wm + j * 16 + col;
      uint2 w;
      w.x = pk2(acc[i][j][0], acc[i][j][1]);
      w.y = pk2(acc[i][j][2], acc[i][j][3]);
      *(uint2*)(R2 + ((size_t)(b * T_ + t) * N_ + m) * KF_ + k * 32 + f) = w;
    }
  }
}

// ---------------- stage 2: out = relu(R2 x Th2^T), MFMA, no LDS ----------------
__global__ __launch_bounds__(256, 2) void stage2(const ushort* __restrict__ R2,
                                                 const ushort* __restrict__ Th2,
                                                 float* __restrict__ Out) {
  const int mh = blockIdx.x;   // 0..1
  const int t = blockIdx.y, b = blockIdx.z;
  const int tid = threadIdx.x, lane = tid & 63, wid = tid >> 6;
  const int m0w = mh * 256 + wid * 64;
  const int col = lane & 15, kc = (lane >> 4) * 8, rg4 = (lane >> 4) * 4;

  bf16x8 bfr[3][4];
#pragma unroll
  for (int ks = 0; ks < 3; ++ks)
#pragma unroll
    for (int j = 0; j < 4; ++j)
      bfr[ks][j] = *(const bf16x8*)(Th2 + (size_t)(j * 16 + col) * KF_ + ks * 32 + kc);

  const ushort* Rb = R2 + ((size_t)b * T_ + t) * N_ * KF_;
  float* Ob = Out + ((size_t)t * B_ + b) * N_ * C_;

#pragma unroll
  for (int i = 0; i < 4; ++i) {
    const int m = m0w + i * 16;
    bf16x8 af[3];
#pragma unroll
    for (int ks = 0; ks < 3; ++ks)
      af[ks] = *(const bf16x8*)(Rb + (size_t)(m + col) * KF_ + ks * 32 + kc);
    f32x4 acc[4];
#pragma unroll
    for (int j = 0; j < 4; ++j) acc[j] = (f32x4){0.f, 0.f, 0.f, 0.f};
#pragma unroll
    for (int ks = 0; ks < 3; ++ks)
#pragma unroll
      for (int j = 0; j < 4; ++j)
        acc[j] = __builtin_amdgcn_mfma_f32_16x16x32_bf16(af[ks], bfr[ks][j], acc[j], 0, 0, 0);
#pragma unroll
    for (int j = 0; j < 4; ++j)
#pragma unroll
      for (int r = 0; r < 4; ++r)
        Ob[(size_t)(m + rg4 + r) * C_ + j * 16 + col] = fmaxf(acc[j][r], 0.f);
  }
}

extern "C" void kernel_launch(void* const* d_in, const int* in_sizes, int n_in,
                              void* d_out, int out_size, void* d_ws, size_t ws_size,
                              hipStream_t stream) {
  const float* X  = (const float*)d_in[0];  // [16,512,32,24]
  const float* SA = (const float*)d_in[1];  // [16,512,512]
  const float* CH = (const float*)d_in[2];  // [3,512,512]
  const float* TH = (const float*)d_in[3];  // [3,32,64]
  float* Out = (float*)d_out;               // [24,16,512,64]

  // ws partition (bytes): R2 37,748,736 | Xt2 12,582,912 | At 25,165,824 | Th2 12,288
  char* ws = (char*)d_ws;
  ushort* R2  = (ushort*)(ws);
  ushort* Xt2 = (ushort*)(ws + 37748736);
  ushort* At  = (ushort*)(ws + 37748736 + 12582912);
  ushort* Th2 = (ushort*)(ws + 37748736 + 12582912 + 25165824);

  prepX<<<dim3(16, 16), 256, 0, stream>>>(X, Xt2);
  prepA<<<dim3(64, 48), 256, 0, stream>>>(SA, CH, At);
  prepTh<<<1, 256, 0, stream>>>(TH, Th2);
  stage1<<<dim3(24, 48), 256, 0, stream>>>(Xt2, At, R2);
  stage2<<<dim3(2, 24, 16), 256, 0, stream>>>(R2, Th2, Out);
}